// Round 1
// baseline (95.535 us; speedup 1.0000x reference)
//
#include <hip/hip_runtime.h>
#include <float.h>
#include <stdint.h>

// CorrLoss via bf16 MFMA, symmetric 128x128 tiles, swizzled LDS.
//   Round 10: (1) K-loop restructured to T3-minimal double-buffered prefetch:
//   stage tile t+1 BEFORE computing tile t, ONE __syncthreads per iter -> the
//   vmcnt(0) drain lands after ~1100cy of ds_read+MFMA, hiding L2 latency
//   (was: stage -> sync -> compute -> sync, full latency exposed x8 iters).
//   (2) fold_kernel deleted: gram reduces straight into ap_m/an_m[4096] via
//   monotone-uint32 atomicMin/Max (exact, order-independent); last-done block
//   (atomic counter, proven pattern) computes the final loss. One less launch
//   gap, -2MB partial traffic. cast_kernel inits ap_m/an_m/counter.

#define N_ROWS 4096
#define D_K    512
#define BT     128
#define BK     64
#define NTB    (N_ROWS / BT)           // 32
#define NTILES (NTB * (NTB + 1) / 2)   // 528
#define NITER  (D_K / BK)              // 8
#define MARGIN 40.0f

typedef __bf16 bf16_t;
typedef bf16_t bf16x8 __attribute__((ext_vector_type(8)));
typedef float  floatx4 __attribute__((ext_vector_type(4)));
typedef unsigned short ushort_t;
typedef ushort_t ushortx8 __attribute__((ext_vector_type(8)));

#define GLOAD_LDS16(g, l)                                        \
    __builtin_amdgcn_global_load_lds(                            \
        (const __attribute__((address_space(1))) void*)(g),      \
        (__attribute__((address_space(3))) void*)(l), 16, 0, 0)

__device__ __forceinline__ ushort_t f2bf_rne(float x) {
    uint32_t u = __builtin_bit_cast(uint32_t, x);
    return (ushort_t)((u + 0x7FFFu + ((u >> 16) & 1u)) >> 16);
}

// monotone order-preserving float<->uint32 (for atomicMin/Max on floats)
__device__ __forceinline__ unsigned int f2mono(float x) {
    uint32_t u = __builtin_bit_cast(uint32_t, x);
    return (u & 0x80000000u) ? ~u : (u | 0x80000000u);
}
__device__ __forceinline__ float mono2f(unsigned int m) {
    uint32_t u = (m & 0x80000000u) ? (m ^ 0x80000000u) : ~m;
    return __builtin_bit_cast(float, u);
}

__global__ __launch_bounds__(256) void cast_kernel(
    const float* __restrict__ f, ushort_t* __restrict__ o,
    unsigned int* __restrict__ ap_m, unsigned int* __restrict__ an_m,
    int* __restrict__ counter)
{
    const int gid = blockIdx.x * 256 + threadIdx.x;
    if (gid == 0) *counter = 0;
    if (gid < N_ROWS) { ap_m[gid] = 0xFFFFFFFFu; an_m[gid] = 0u; }

    const int i = gid * 8;
    const float4 v0 = *(const float4*)(f + i);
    const float4 v1 = *(const float4*)(f + i + 4);
    ushortx8 r;
    r[0] = f2bf_rne(v0.x); r[1] = f2bf_rne(v0.y);
    r[2] = f2bf_rne(v0.z); r[3] = f2bf_rne(v0.w);
    r[4] = f2bf_rne(v1.x); r[5] = f2bf_rne(v1.y);
    r[6] = f2bf_rne(v1.z); r[7] = f2bf_rne(v1.w);
    *(ushortx8*)(o + i) = r;
}

__global__ __launch_bounds__(512, 4) void gram_mfma_kernel(
    const ushort_t* __restrict__ fb, const int* __restrict__ tgt,
    unsigned int* __restrict__ ap_m, unsigned int* __restrict__ an_m,
    int* __restrict__ counter, float* __restrict__ out)
{
    // [row][k] row-major, row stride 64 bf16 = 128 B; 16 B k-chunks
    // XOR-swizzled: physical chunk p holds global chunk p ^ (row & 7).
    // Double-buffered: As/Bs[2], prefetch-ahead-1.
    __shared__ __align__(16) ushort_t As[2][BT * BK];   // 32 KB
    __shared__ __align__(16) ushort_t Bs[2][BT * BK];   // 32 KB
    __shared__ int tgI[BT];
    __shared__ int tgJ[BT];
    __shared__ int s_last;

    // epilogue reductions alias As[0] (used only after final tile -> As[1])
    float* apRed  = (float*)As;          // [4][BT]
    float* anRed  = apRed  + 4 * BT;     // [4][BT]
    float* apRedT = anRed  + 4 * BT;     // [2][BT]
    float* anRedT = apRedT + 2 * BT;     // [2][BT]   total 6 KB <= 16 KB

    // flat block id -> upper-tri (bi, bj), row-major
    int bi = 0, rem = blockIdx.x;
    while (rem >= NTB - bi) { rem -= NTB - bi; ++bi; }
    const int bj = bi + rem;

    const int tid  = threadIdx.x;
    const int i0   = bi * BT;
    const int j0   = bj * BT;
    const int lane = tid & 63;
    const int wave = tid >> 6;
    const int wr   = wave >> 2;      // row half (0/1): 64 rows
    const int wc   = wave & 3;       // col quarter (0..3): 32 cols
    const int lr   = lane & 15;      // frag row (A/B) / col (C/D)
    const int lg   = lane >> 4;      // k-group (A/B) / row-quad (C/D)
    const int sw   = lr & 7;         // read-side swizzle key

    if (tid < BT)            tgI[tid]      = tgt[i0 + tid];
    else if (tid < 2 * BT)   tgJ[tid - BT] = tgt[j0 + tid - BT];

    // staging: thread t -> row t>>3 (and +64), physical chunk t&7 holds
    // global chunk (t&7)^(row&7); dest = tid*16 (lane-contiguous per wave)
    const int srow = tid >> 3;
    const int schk = (tid & 7) ^ (srow & 7);
    const size_t gA0 = (size_t)(i0 + srow) * D_K + schk * 8;
    const size_t gB0 = (size_t)(j0 + srow) * D_K + schk * 8;
    const size_t gHi = (size_t)64 * D_K;

#define STAGE(buf, kk) do {                                          \
        char* aD = (char*)As[buf]; char* bD = (char*)Bs[buf];        \
        GLOAD_LDS16(fb + gA0 + (kk),       aD + tid * 16);           \
        GLOAD_LDS16(fb + gA0 + gHi + (kk), aD + 8192 + tid * 16);    \
        GLOAD_LDS16(fb + gB0 + (kk),       bD + tid * 16);           \
        GLOAD_LDS16(fb + gB0 + gHi + (kk), bD + 8192 + tid * 16);    \
    } while (0)

    floatx4 acc[4][2];
#pragma unroll
    for (int a = 0; a < 4; ++a)
#pragma unroll
        for (int b = 0; b < 2; ++b) acc[a][b] = (floatx4)0.0f;

    STAGE(0, 0);
    __syncthreads();          // drain prologue stage (vmcnt(0) + barrier)

    int cur = 0;
#pragma unroll
    for (int t = 0; t < NITER; ++t) {
        if (t + 1 < NITER) STAGE(cur ^ 1, (t + 1) * BK);   // prefetch next

        const ushort_t* Acur = As[cur];
        const ushort_t* Bcur = Bs[cur];
        // two sequential k-halves; frag regs scoped per-half (VGPR diet)
#pragma unroll
        for (int h = 0; h < 2; ++h) {
            bf16x8 af[4], bfr[2];
            const int pc = ((h * 4 + lg) ^ sw) * 8;   // swizzled chunk (elems)
#pragma unroll
            for (int rg = 0; rg < 4; ++rg)
                af[rg] = *(const bf16x8*)(Acur + (wr * 64 + rg * 16 + lr) * BK + pc);
#pragma unroll
            for (int cg = 0; cg < 2; ++cg)
                bfr[cg] = *(const bf16x8*)(Bcur + (wc * 32 + cg * 16 + lr) * BK + pc);
#pragma unroll
            for (int rg = 0; rg < 4; ++rg)
#pragma unroll
                for (int cg = 0; cg < 2; ++cg)
                    acc[rg][cg] = __builtin_amdgcn_mfma_f32_16x16x32_bf16(
                        af[rg], bfr[cg], acc[rg][cg], 0, 0, 0);
        }
        if (t + 1 < NITER) {
            __syncthreads();   // vmcnt(0): prefetch arrived under compute
            cur ^= 1;
        }
    }

    // ---- epilogue: C/D frag layout: col = lr, row = lg*4 + reg ----
    // (apRed aliases As[0]; final tile lives in As[1]/Bs[1] -> disjoint)
    int tj[2];
#pragma unroll
    for (int cg = 0; cg < 2; ++cg) tj[cg] = tgJ[wc * 32 + cg * 16 + lr];

    float apT[2], anT[2];
#pragma unroll
    for (int cg = 0; cg < 2; ++cg) { apT[cg] = FLT_MAX; anT[cg] = -FLT_MAX; }

#pragma unroll
    for (int rg = 0; rg < 4; ++rg) {
#pragma unroll
        for (int r = 0; r < 4; ++r) {
            const int rloc = wr * 64 + rg * 16 + lg * 4 + r;
            const int ti = tgI[rloc];
            float vap = FLT_MAX, van = -FLT_MAX;
#pragma unroll
            for (int cg = 0; cg < 2; ++cg) {
                const float v = acc[rg][cg][r];
                if (ti == tj[cg]) { vap = fminf(vap, v); apT[cg] = fminf(apT[cg], v); }
                else              { van = fmaxf(van, v); anT[cg] = fmaxf(anT[cg], v); }
            }
            // direct: fold the 16 cols held by lanes lr=0..15
#pragma unroll
            for (int m = 1; m < 16; m <<= 1) {
                vap = fminf(vap, __shfl_xor(vap, m));
                van = fmaxf(van, __shfl_xor(van, m));
            }
            if (lr == 0) { apRed[wc * BT + rloc] = vap; anRed[wc * BT + rloc] = van; }
        }
    }
    // transposed: rows folded in-lane; fold the 4 lane-groups
#pragma unroll
    for (int cg = 0; cg < 2; ++cg) {
        float vap = apT[cg], van = anT[cg];
        vap = fminf(vap, __shfl_xor(vap, 16)); van = fmaxf(van, __shfl_xor(van, 16));
        vap = fminf(vap, __shfl_xor(vap, 32)); van = fmaxf(van, __shfl_xor(van, 32));
        if (lg == 0) {
            apRedT[wr * BT + wc * 32 + cg * 16 + lr] = vap;
            anRedT[wr * BT + wc * 32 + cg * 16 + lr] = van;
        }
    }
    __syncthreads();

    if (tid < BT) {
        const float ap = fminf(fminf(apRed[0 * BT + tid], apRed[1 * BT + tid]),
                               fminf(apRed[2 * BT + tid], apRed[3 * BT + tid]));
        const float an = fmaxf(fmaxf(anRed[0 * BT + tid], anRed[1 * BT + tid]),
                               fmaxf(anRed[2 * BT + tid], anRed[3 * BT + tid]));
        atomicMin(ap_m + i0 + tid, f2mono(ap));
        atomicMax(an_m + i0 + tid, f2mono(an));
        if (bi != bj) {
            atomicMin(ap_m + j0 + tid,
                      f2mono(fminf(apRedT[0 * BT + tid], apRedT[1 * BT + tid])));
            atomicMax(an_m + j0 + tid,
                      f2mono(fmaxf(anRedT[0 * BT + tid], anRedT[1 * BT + tid])));
        }
    }

    // ---- last-done block computes the loss (proven counter pattern) ----
    __syncthreads();           // drains vmcnt -> this block's atomics complete
    if (tid == 0) {
        __threadfence();
        s_last = (atomicAdd(counter, 1) == NTILES - 1) ? 1 : 0;
    }
    __syncthreads();

    if (s_last) {
        __threadfence();
        float local = 0.0f;
#pragma unroll
        for (int q = 0; q < N_ROWS / 512; ++q) {
            const int r = q * 512 + tid;
            // atomic RMW reads: coherent at device scope, value-neutral
            const float ap = mono2f(atomicOr(ap_m + r, 0u));
            const float an = mono2f(atomicOr(an_m + r, 0u));
            const float v  = an - ap + MARGIN;
            local += (v > 0.0f) ? v : 0.0f;
        }
#pragma unroll
        for (int m = 32; m >= 1; m >>= 1) local += __shfl_down(local, m);
        float* fin = (float*)Bs;   // alias Bs[0]; all compute long done
        if (lane == 0) fin[wave] = local;
        __syncthreads();
        if (tid == 0) {
            float s = 0.0f;
#pragma unroll
            for (int w = 0; w < 8; ++w) s += fin[w];
            out[0] = s * (1.0f / N_ROWS);
        }
    }
#undef STAGE
}

extern "C" void kernel_launch(void* const* d_in, const int* in_sizes, int n_in,
                              void* d_out, int out_size, void* d_ws, size_t ws_size,
                              hipStream_t stream)
{
    const float* feat = (const float*)d_in[0];
    const int*   tgt  = (const int*)d_in[1];

    ushort_t*     fb   = (ushort_t*)d_ws;                       // 4 MB bf16 feat
    unsigned int* ap_m = (unsigned int*)(fb + (size_t)N_ROWS * D_K);  // 16 KB
    unsigned int* an_m = ap_m + N_ROWS;                         // 16 KB
    int*          counter = (int*)(an_m + N_ROWS);

    cast_kernel<<<(N_ROWS * D_K) / (256 * 8), 256, 0, stream>>>(
        feat, fb, ap_m, an_m, counter);
    gram_mfma_kernel<<<NTILES, 512, 0, stream>>>(
        fb, tgt, ap_m, an_m, counter, (float*)d_out);
}

// Round 2
// 84.813 us; speedup vs baseline: 1.1264x; 1.1264x over previous
//
#include <hip/hip_runtime.h>
#include <float.h>
#include <stdint.h>

// CorrLoss via bf16 MFMA, symmetric 128x128 tiles, swizzled LDS.
//   Round 11: clean A/B vs R9 (86.4us) and R10 (95.5us, regressed).
//   R10 changed two things at once; this round isolates them:
//   - K-loop REVERTED to R9's proven single-buffer 2-barrier structure
//     (33.5 KB LDS, launch_bounds(512,6) -> 3 blocks/CU; R10's dbuf doubled
//     LDS -> 2 blocks/CU, the likely regression per m99/m132).
//   - Fused fold KEPT: gram reduces into ap_m/an_m[4096] via monotone-uint32
//     atomicMin/Max (exact, order-independent, replay-deterministic); the
//     last-done block (atomic counter) computes the loss. One less launch
//     gap, -2MB partial traffic, fold_kernel deleted.
//   k0: cast fp32->bf16 (RNE); init ap_m/an_m/counter.
//   k1: 528 upper-tri tiles, 8 waves x (64x32 patch), BK=64, XOR-swizzled
//       global_load_lds w=16 staging; atomic min/max epilogue + fused loss.

#define N_ROWS 4096
#define D_K    512
#define BT     128
#define BK     64
#define NTB    (N_ROWS / BT)           // 32
#define NTILES (NTB * (NTB + 1) / 2)   // 528
#define MARGIN 40.0f

typedef __bf16 bf16_t;
typedef bf16_t bf16x8 __attribute__((ext_vector_type(8)));
typedef float  floatx4 __attribute__((ext_vector_type(4)));
typedef unsigned short ushort_t;
typedef ushort_t ushortx8 __attribute__((ext_vector_type(8)));

#define GLOAD_LDS16(g, l)                                        \
    __builtin_amdgcn_global_load_lds(                            \
        (const __attribute__((address_space(1))) void*)(g),      \
        (__attribute__((address_space(3))) void*)(l), 16, 0, 0)

__device__ __forceinline__ ushort_t f2bf_rne(float x) {
    uint32_t u = __builtin_bit_cast(uint32_t, x);
    return (ushort_t)((u + 0x7FFFu + ((u >> 16) & 1u)) >> 16);
}

// monotone order-preserving float<->uint32 (for atomicMin/Max on floats)
__device__ __forceinline__ unsigned int f2mono(float x) {
    uint32_t u = __builtin_bit_cast(uint32_t, x);
    return (u & 0x80000000u) ? ~u : (u | 0x80000000u);
}
__device__ __forceinline__ float mono2f(unsigned int m) {
    uint32_t u = (m & 0x80000000u) ? (m ^ 0x80000000u) : ~m;
    return __builtin_bit_cast(float, u);
}

__global__ __launch_bounds__(256) void cast_kernel(
    const float* __restrict__ f, ushort_t* __restrict__ o,
    unsigned int* __restrict__ ap_m, unsigned int* __restrict__ an_m,
    int* __restrict__ counter)
{
    const int gid = blockIdx.x * 256 + threadIdx.x;
    if (gid == 0) *counter = 0;
    if (gid < N_ROWS) { ap_m[gid] = 0xFFFFFFFFu; an_m[gid] = 0u; }

    const int i = gid * 8;
    const float4 v0 = *(const float4*)(f + i);
    const float4 v1 = *(const float4*)(f + i + 4);
    ushortx8 r;
    r[0] = f2bf_rne(v0.x); r[1] = f2bf_rne(v0.y);
    r[2] = f2bf_rne(v0.z); r[3] = f2bf_rne(v0.w);
    r[4] = f2bf_rne(v1.x); r[5] = f2bf_rne(v1.y);
    r[6] = f2bf_rne(v1.z); r[7] = f2bf_rne(v1.w);
    *(ushortx8*)(o + i) = r;
}

__global__ __launch_bounds__(512, 6) void gram_mfma_kernel(
    const ushort_t* __restrict__ fb, const int* __restrict__ tgt,
    unsigned int* __restrict__ ap_m, unsigned int* __restrict__ an_m,
    int* __restrict__ counter, float* __restrict__ out)
{
    // [row][k] row-major, row stride 64 bf16 = 128 B; 16 B k-chunks
    // XOR-swizzled: physical chunk p holds global chunk p ^ (row & 7).
    __shared__ __align__(16) ushort_t As[BT * BK];   // 16 KB
    __shared__ __align__(16) ushort_t Bs[BT * BK];   // 16 KB
    __shared__ int tgI[BT];
    __shared__ int tgJ[BT];
    __shared__ int s_last;

    // epilogue reductions alias As (used only after the K-loop's last barrier)
    float* apRed  = (float*)As;          // [4][BT]
    float* anRed  = apRed  + 4 * BT;     // [4][BT]
    float* apRedT = anRed  + 4 * BT;     // [2][BT]
    float* anRedT = apRedT + 2 * BT;     // [2][BT]   total 6 KB <= 16 KB

    // flat block id -> upper-tri (bi, bj), row-major
    int bi = 0, rem = blockIdx.x;
    while (rem >= NTB - bi) { rem -= NTB - bi; ++bi; }
    const int bj = bi + rem;

    const int tid  = threadIdx.x;
    const int i0   = bi * BT;
    const int j0   = bj * BT;
    const int lane = tid & 63;
    const int wave = tid >> 6;
    const int wr   = wave >> 2;      // row half (0/1): 64 rows
    const int wc   = wave & 3;       // col quarter (0..3): 32 cols
    const int lr   = lane & 15;      // frag row (A/B) / col (C/D)
    const int lg   = lane >> 4;      // k-group (A/B) / row-quad (C/D)
    const int sw   = lr & 7;         // read-side swizzle key

    if (tid < BT)            tgI[tid]      = tgt[i0 + tid];
    else if (tid < 2 * BT)   tgJ[tid - BT] = tgt[j0 + tid - BT];

    // staging: thread t -> row t>>3 (and +64), physical chunk t&7 holds
    // global chunk (t&7)^(row&7); dest = tid*16 (lane-contiguous per wave)
    const int srow = tid >> 3;
    const int schk = (tid & 7) ^ (srow & 7);
    const size_t gA0 = (size_t)(i0 + srow) * D_K + schk * 8;
    const size_t gB0 = (size_t)(j0 + srow) * D_K + schk * 8;
    const size_t gHi = (size_t)64 * D_K;
    char* AsB = (char*)As;
    char* BsB = (char*)Bs;

    floatx4 acc[4][2];
#pragma unroll
    for (int a = 0; a < 4; ++a)
#pragma unroll
        for (int b = 0; b < 2; ++b) acc[a][b] = (floatx4)0.0f;

    for (int k0 = 0; k0 < D_K; k0 += BK) {
        GLOAD_LDS16(fb + gA0 + k0,       AsB + tid * 16);
        GLOAD_LDS16(fb + gA0 + gHi + k0, AsB + 8192 + tid * 16);
        GLOAD_LDS16(fb + gB0 + k0,       BsB + tid * 16);
        GLOAD_LDS16(fb + gB0 + gHi + k0, BsB + 8192 + tid * 16);
        __syncthreads();

        // two sequential k-halves; frag regs scoped per-half (VGPR diet)
#pragma unroll
        for (int h = 0; h < 2; ++h) {
            bf16x8 af[4], bfr[2];
            const int pc = ((h * 4 + lg) ^ sw) * 8;   // swizzled chunk (elems)
#pragma unroll
            for (int rg = 0; rg < 4; ++rg)
                af[rg] = *(const bf16x8*)(As + (wr * 64 + rg * 16 + lr) * BK + pc);
#pragma unroll
            for (int cg = 0; cg < 2; ++cg)
                bfr[cg] = *(const bf16x8*)(Bs + (wc * 32 + cg * 16 + lr) * BK + pc);
#pragma unroll
            for (int rg = 0; rg < 4; ++rg)
#pragma unroll
                for (int cg = 0; cg < 2; ++cg)
                    acc[rg][cg] = __builtin_amdgcn_mfma_f32_16x16x32_bf16(
                        af[rg], bfr[cg], acc[rg][cg], 0, 0, 0);
        }
        __syncthreads();
    }

    // ---- epilogue: C/D frag layout: col = lr, row = lg*4 + reg ----
    int tj[2];
#pragma unroll
    for (int cg = 0; cg < 2; ++cg) tj[cg] = tgJ[wc * 32 + cg * 16 + lr];

    float apT[2], anT[2];
#pragma unroll
    for (int cg = 0; cg < 2; ++cg) { apT[cg] = FLT_MAX; anT[cg] = -FLT_MAX; }

#pragma unroll
    for (int rg = 0; rg < 4; ++rg) {
#pragma unroll
        for (int r = 0; r < 4; ++r) {
            const int rloc = wr * 64 + rg * 16 + lg * 4 + r;
            const int ti = tgI[rloc];
            float vap = FLT_MAX, van = -FLT_MAX;
#pragma unroll
            for (int cg = 0; cg < 2; ++cg) {
                const float v = acc[rg][cg][r];
                if (ti == tj[cg]) { vap = fminf(vap, v); apT[cg] = fminf(apT[cg], v); }
                else              { van = fmaxf(van, v); anT[cg] = fmaxf(anT[cg], v); }
            }
            // direct: fold the 16 cols held by lanes lr=0..15
#pragma unroll
            for (int m = 1; m < 16; m <<= 1) {
                vap = fminf(vap, __shfl_xor(vap, m));
                van = fmaxf(van, __shfl_xor(van, m));
            }
            if (lr == 0) { apRed[wc * BT + rloc] = vap; anRed[wc * BT + rloc] = van; }
        }
    }
    // transposed: rows folded in-lane; fold the 4 lane-groups
#pragma unroll
    for (int cg = 0; cg < 2; ++cg) {
        float vap = apT[cg], van = anT[cg];
        vap = fminf(vap, __shfl_xor(vap, 16)); van = fmaxf(van, __shfl_xor(van, 16));
        vap = fminf(vap, __shfl_xor(vap, 32)); van = fmaxf(van, __shfl_xor(van, 32));
        if (lg == 0) {
            apRedT[wr * BT + wc * 32 + cg * 16 + lr] = vap;
            anRedT[wr * BT + wc * 32 + cg * 16 + lr] = van;
        }
    }
    __syncthreads();

    if (tid < BT) {
        const float ap = fminf(fminf(apRed[0 * BT + tid], apRed[1 * BT + tid]),
                               fminf(apRed[2 * BT + tid], apRed[3 * BT + tid]));
        const float an = fmaxf(fmaxf(anRed[0 * BT + tid], anRed[1 * BT + tid]),
                               fmaxf(anRed[2 * BT + tid], anRed[3 * BT + tid]));
        atomicMin(ap_m + i0 + tid, f2mono(ap));
        atomicMax(an_m + i0 + tid, f2mono(an));
        if (bi != bj) {
            atomicMin(ap_m + j0 + tid,
                      f2mono(fminf(apRedT[0 * BT + tid], apRedT[1 * BT + tid])));
            atomicMax(an_m + j0 + tid,
                      f2mono(fmaxf(anRedT[0 * BT + tid], anRedT[1 * BT + tid])));
        }
    }

    // ---- last-done block computes the loss (proven counter pattern) ----
    __syncthreads();           // all waves' atomics issued before the count
    if (tid == 0) {
        __threadfence();
        s_last = (atomicAdd(counter, 1) == NTILES - 1) ? 1 : 0;
    }
    __syncthreads();

    if (s_last) {
        __threadfence();
        float local = 0.0f;
#pragma unroll
        for (int q = 0; q < N_ROWS / 512; ++q) {
            const int r = q * 512 + tid;
            // atomic RMW reads: coherent at device scope, value-neutral
            const float ap = mono2f(atomicOr(ap_m + r, 0u));
            const float an = mono2f(atomicOr(an_m + r, 0u));
            const float v  = an - ap + MARGIN;
            local += (v > 0.0f) ? v : 0.0f;
        }
#pragma unroll
        for (int m = 32; m >= 1; m >>= 1) local += __shfl_down(local, m);
        float* fin = (float*)Bs;   // alias Bs; all compute long done
        if (lane == 0) fin[wave] = local;
        __syncthreads();
        if (tid == 0) {
            float s = 0.0f;
#pragma unroll
            for (int w = 0; w < 8; ++w) s += fin[w];
            out[0] = s * (1.0f / N_ROWS);
        }
    }
}

extern "C" void kernel_launch(void* const* d_in, const int* in_sizes, int n_in,
                              void* d_out, int out_size, void* d_ws, size_t ws_size,
                              hipStream_t stream)
{
    const float* feat = (const float*)d_in[0];
    const int*   tgt  = (const int*)d_in[1];

    ushort_t*     fb   = (ushort_t*)d_ws;                       // 4 MB bf16 feat
    unsigned int* ap_m = (unsigned int*)(fb + (size_t)N_ROWS * D_K);  // 16 KB
    unsigned int* an_m = ap_m + N_ROWS;                         // 16 KB
    int*          counter = (int*)(an_m + N_ROWS);

    cast_kernel<<<(N_ROWS * D_K) / (256 * 8), 256, 0, stream>>>(
        feat, fb, ap_m, an_m, counter);
    gram_mfma_kernel<<<NTILES, 512, 0, stream>>>(
        fb, tgt, ap_m, an_m, counter, (float*)d_out);
}